// Round 2
// 465.563 us; speedup vs baseline: 1.0487x; 1.0487x over previous
//
#include <hip/hip_runtime.h>

// Problem constants (reference: B=2, S=8192, D_MODEL=768, H=12, R=4, SEG=512)
constexpr int Bb   = 2;
constexpr int S    = 8192;
constexpr int D    = 768;
constexpr int H    = 12;
constexpr int HD   = 64;     // head dim
constexpr int R    = 4;      // dilation offsets
constexpr int L    = 2048;   // S / R tokens per offset
constexpr int SEG  = 512;
constexpr int NSEG = 4;      // L / SEG
constexpr int E3   = 3 * D;  // 2304 fused qkv dim
constexpr int RD   = R * D;  // 3072 output feature dim

typedef _Float16 f16x8 __attribute__((ext_vector_type(8)));
typedef _Float16 f16x4 __attribute__((ext_vector_type(4)));
typedef float    f32x4 __attribute__((ext_vector_type(4)));

#define AS1 __attribute__((address_space(1)))
#define AS3 __attribute__((address_space(3)))

// async global->LDS, 16B per lane; LDS dest is wave-uniform base + lane*16
__device__ __forceinline__ void gld16(const void* g, void* l) {
    __builtin_amdgcn_global_load_lds((AS1 void*)g, (AS3 void*)l, 16, 0, 0);
}

__global__ __launch_bounds__(256) void conv_one(const float4* __restrict__ x,
                                                f16x4* __restrict__ o, int n4)
{
    int i = blockIdx.x * 256 + threadIdx.x;
    const int stride = gridDim.x * 256;
    for (; i < n4; i += stride) {
        float4 v = x[i];
        f16x4 h;
        h[0] = (_Float16)v.x; h[1] = (_Float16)v.y;
        h[2] = (_Float16)v.z; h[3] = (_Float16)v.w;
        o[i] = h;
    }
}

// ---------------------------------------------------------------------------
// MFMA GEMM. 128x128 tile, BK=32, 4 waves (2x2 of 64x64), 16x16x32_f16.
// Round 7: 3-buffer counted-vmcnt pipeline (stage 2 tiles ahead, raw
// s_barrier, s_waitcnt vmcnt(4) instead of the __syncthreads vmcnt(0) drain)
// + bijective XCD swizzle (one z per XCD: A panel 3MB + W 3.4MB ~ L2).
// Safety invariant: lgkmcnt(0) precedes every barrier, so a DMA issued after
// the barrier only targets a buffer whose readers (tile k-1) are drained.
// MODE 0: QKV proj (A dilated, lda=3072; N=2304). Epilogue: Q/K row-major
//         f16 via LDS bounce; V direct to transposed [z][h][ns][hd][key].
// MODE 1: out proj; fp32 C scattered into res layout (ldc=12288). N=768.
//         Also writes the structural zeros of the other 3 offsets' column
//         slots (replaces the zero_fill kernel; one writer per output byte).
// ---------------------------------------------------------------------------
template <int MODE>
__global__ __launch_bounds__(256) void mfma_gemm(const _Float16* __restrict__ Ah0,
                                                 const _Float16* __restrict__ Wh0,
                                                 const float* __restrict__ B0,
                                                 _Float16* __restrict__ Q0,
                                                 _Float16* __restrict__ K0,
                                                 _Float16* __restrict__ V0,
                                                 float* __restrict__ C0)
{
    constexpr int NXB = (MODE == 0) ? 18 : 6;      // N-blocks per z
    constexpr int NWG = NXB * 16 * 8;              // total workgroups (%8==0)
    const int wg = ((int)blockIdx.x & 7) * (NWG >> 3) + ((int)blockIdx.x >> 3);
    const int n0 = (wg % NXB) * 128;
    const int m0 = ((wg / NXB) & 15) * 128;
    const int z  = wg / (NXB * 16);                // z = r*2 + b
    const int r = z >> 1, b = z & 1;

    const _Float16* Ah; const _Float16* Wh; const float* bias;
    int lda;
    if (MODE == 0) {
        Ah = Ah0 + ((size_t)b * S + r) * D;  lda = RD;    // dilated stride 3072
        Wh = Wh0 + (size_t)r * E3 * D;
        bias = B0 + r * E3;
    } else {
        Ah = Ah0 + (size_t)z * L * D;        lda = D;
        Wh = Wh0 + (size_t)r * D * D;
        bias = B0 + r * D;
    }

    const int tid  = threadIdx.x;
    const int wave = tid >> 6;
    const int lane = tid & 63;
    const int lw   = lane & 15;
    const int quad = lane >> 4;
    const int wm   = wave & 1, wn = wave >> 1;

    __shared__ _Float16 sm[3][2][4096];   // [buf][tile: 0=A 1=W], 48 KB

    f32x4 acc[4][4];
    #pragma unroll
    for (int mt = 0; mt < 4; mt++)
        #pragma unroll
        for (int nt = 0; nt < 4; nt++)
            acc[mt][nt] = f32x4{0.f, 0.f, 0.f, 0.f};

    const int srow = lane & 15;          // row within mgroup
    const int scol = (lane >> 4) * 8;    // k-chunk * 8 f16

    // 16 gld16 per k-step (2 tiles x 8 mgroups), 4 per wave
    auto stage = [&](int buf, int k0) {
        #pragma unroll
        for (int i = 0; i < 4; i++) {
            const int idx  = wave * 4 + i;
            const int tile = idx >> 3, g = idx & 7;
            const _Float16* src = (tile == 0) ? Ah : Wh;
            const int ldr   = (tile == 0) ? lda : D;
            const int base0 = (tile == 0) ? m0 : n0;
            gld16(src + (size_t)(base0 + g * 16 + srow) * ldr + k0 + scol,
                  &sm[buf][tile][g * 512]);
        }
    };

    stage(0, 0);
    stage(1, 32);

    for (int k = 0; k < 24; k++) {
        // all my LDS reads from iter k-1 are complete before anyone passes
        // the barrier -> staging into buffer (k-1)%3 afterwards is race-free
        asm volatile("s_waitcnt lgkmcnt(0)" ::: "memory");
        if (k == 23) asm volatile("s_waitcnt vmcnt(0)" ::: "memory");
        else         asm volatile("s_waitcnt vmcnt(4)" ::: "memory");  // tile k landed, tile k+1 in flight
        __builtin_amdgcn_s_barrier();
        __builtin_amdgcn_sched_barrier(0);   // no frag read hoists above barrier

        const int buf = k % 3;
        f16x8 af[4], bf[4];
        #pragma unroll
        for (int mt = 0; mt < 4; mt++)
            af[mt] = *(const f16x8*)&sm[buf][0][(wm * 4 + mt) * 512 + quad * 128 + lw * 8];
        #pragma unroll
        for (int nt = 0; nt < 4; nt++)
            bf[nt] = *(const f16x8*)&sm[buf][1][(wn * 4 + nt) * 512 + quad * 128 + lw * 8];
        if (k + 2 < 24) stage((k + 2) % 3, (k + 2) * 32);
        #pragma unroll
        for (int mt = 0; mt < 4; mt++)
            #pragma unroll
            for (int nt = 0; nt < 4; nt++)
                acc[mt][nt] = __builtin_amdgcn_mfma_f32_16x16x32_f16(af[mt], bf[nt], acc[mt][nt], 0, 0, 0);
    }
    __syncthreads();   // staging LDS reused as epilogue bounce buffer

    float bv[4];
    #pragma unroll
    for (int nt = 0; nt < 4; nt++)
        bv[nt] = bias[n0 + wn * 64 + nt * 16 + lw];

    if (MODE == 0) {
        const int reg = n0 / D;            // 0=Q, 1=K, 2=V (128 | 768)
        if (reg < 2) {
            _Float16* G = (reg == 0 ? Q0 : K0) + (size_t)z * L * D;
            const int colbase = (n0 - reg * D) + wn * 64;
            _Float16* wbuf = &sm[0][0][wave * 2048];    // 32x64 f16 per wave
            #pragma unroll
            for (int p = 0; p < 2; p++) {
                #pragma unroll
                for (int mtl = 0; mtl < 2; mtl++) {
                    const int mt = p * 2 + mtl;
                    #pragma unroll
                    for (int nt = 0; nt < 4; nt++)
                        #pragma unroll
                        for (int rr = 0; rr < 4; rr++)
                            wbuf[(mtl * 16 + quad * 4 + rr) * 64 + nt * 16 + lw] =
                                (_Float16)(acc[mt][nt][rr] + bv[nt]);
                }
                asm volatile("s_waitcnt lgkmcnt(0)" ::: "memory");
                #pragma unroll
                for (int j = 0; j < 4; j++) {
                    const int rl = (lane >> 3) + j * 8;
                    f16x8 v = *(const f16x8*)&wbuf[rl * 64 + (lane & 7) * 8];
                    const int l = m0 + wm * 64 + p * 32 + rl;
                    *(f16x8*)(G + (size_t)l * D + colbase + (lane & 7) * 8) = v;
                }
                asm volatile("s_waitcnt lgkmcnt(0)" ::: "memory");
            }
        } else {
            #pragma unroll
            for (int nt = 0; nt < 4; nt++) {
                const int e  = (n0 - 2 * D) + wn * 64 + nt * 16 + lw;  // 0..767
                const int hh = e >> 6, hd = e & 63;
                #pragma unroll
                for (int mt = 0; mt < 4; mt++) {
                    const int l = m0 + wm * 64 + mt * 16 + quad * 4;
                    const int ns = l >> 9, key = l & 511;
                    f16x4 v;
                    #pragma unroll
                    for (int rr = 0; rr < 4; rr++)
                        v[rr] = (_Float16)(acc[mt][nt][rr] + bv[nt]);
                    *(f16x4*)(V0 + ((size_t)((z * H + hh) * NSEG + ns)) * (HD * SEG)
                              + (size_t)hd * SEG + key) = v;
                }
            }
        }
    } else {
        // out[b][s][c]: s = l*R + r, c = rp*D + col; value at rp==r, zeros else
        float* Crow = C0 + (size_t)b * S * RD;
        #pragma unroll
        for (int mt = 0; mt < 4; mt++)
            #pragma unroll
            for (int nt = 0; nt < 4; nt++) {
                const int col = n0 + wn * 64 + nt * 16 + lw;
                #pragma unroll
                for (int rr = 0; rr < 4; rr++) {
                    const int l = m0 + wm * 64 + mt * 16 + quad * 4 + rr;
                    const float val = acc[mt][nt][rr] + bv[nt];
                    const size_t rowoff = (size_t)(l * R + r) * RD;
                    #pragma unroll
                    for (int rp = 0; rp < 4; rp++)
                        Crow[rowoff + rp * D + col] = (rp == r) ? val : 0.f;
                }
            }
    }
}

// ---------------------------------------------------------------------------
// MFMA flash attention. S^T = K Q^T; conflict-free chunked LDS layout
// [grp16][chunk][sub16][8]; Q/K/V staged with global_load_lds width-16.
// Round 7: K/V staging triple-buffered with counted vmcnt(4) (was: stage ->
// full vmcnt(0) drain -> compute, serial every kt). One barrier per kt;
// lgkmcnt(0)-before-barrier invariant as in the GEMM. XCD swizzle on grid.
// ---------------------------------------------------------------------------
__global__ __launch_bounds__(256) void attn_mfma(const _Float16* __restrict__ Qh,
                                                 const _Float16* __restrict__ Kh,
                                                 const _Float16* __restrict__ Vt,
                                                 _Float16* __restrict__ ctx)
{
    __shared__ _Float16 Ks[3][4096];    // [kg 4][hdchunk 8][ks 16][8], 24KB
    __shared__ _Float16 Vs[3][4096];    // [hg 4][keychunk 8][hs 16][8], 24KB
    __shared__ _Float16 Pw[16384];      // Q staging, then per-wave P, 32KB

    int t = ((int)blockIdx.x & 7) * 96 + ((int)blockIdx.x >> 3);  // XCD swizzle (768%8==0)
    const int qh = t & 1; t >>= 1;
    const int h  = t % H; t /= H;
    const int n  = t & 3; t >>= 2;
    const int z  = t;

    const int tid  = threadIdx.x;
    const int wave = tid >> 6;
    const int lane = tid & 63;
    const int lw   = lane & 15;
    const int quad = lane >> 4;
    const int srow = lane & 15;          // sub-row within group
    const int scol = (lane >> 4) * 8;    // chunk*8 within a 4-chunk half

    // ---- stage Q (256 q x 64 hd): [qg 16][chunk 8][qs 16][8] in Pw ----
    const _Float16* Qg = Qh + ((size_t)(z * L + n * SEG + qh * 256)) * D + h * HD;
    #pragma unroll
    for (int i = 0; i < 8; i++) {
        const int qg = wave * 4 + (i >> 1), h2 = i & 1;
        gld16(Qg + (size_t)(qg * 16 + srow) * D + h2 * 32 + scol,
              &Pw[qg * 1024 + h2 * 512]);
    }
    __syncthreads();

    f16x8 qf[4][2];
    #pragma unroll
    for (int mt = 0; mt < 4; mt++)
        #pragma unroll
        for (int kk = 0; kk < 2; kk++)
            qf[mt][kk] = *(const f16x8*)&Pw[(wave * 4 + mt) * 1024 + (kk * 4 + quad) * 128 + lw * 8];

    const _Float16* Kg = Kh + ((size_t)(z * L + n * SEG)) * D + h * HD;
    const _Float16* Vg = Vt + ((size_t)((z * H + h) * NSEG + n)) * (HD * SEG);
    _Float16* Pv = Pw + wave * 4096;

    // ---- stage K,V chunk kt into buf: 16 gld16, 4 per wave ----
    auto stageKV = [&](int buf, int kt) {
        #pragma unroll
        for (int i = 0; i < 4; i++) {
            const int idx = wave * 4 + i;          // 0..15
            const int j = idx & 7, g = j >> 1, h2 = j & 1;
            if (idx < 8)
                gld16(Kg + (size_t)(kt * 64 + g * 16 + srow) * D + h2 * 32 + scol,
                      &Ks[buf][g * 1024 + h2 * 512]);
            else
                gld16(Vg + (size_t)(g * 16 + srow) * SEG + kt * 64 + h2 * 32 + scol,
                      &Vs[buf][g * 1024 + h2 * 512]);
        }
    };

    f32x4 cacc[4][4];
    #pragma unroll
    for (int mt = 0; mt < 4; mt++)
        #pragma unroll
        for (int nt = 0; nt < 4; nt++)
            cacc[mt][nt] = f32x4{0.f, 0.f, 0.f, 0.f};
    float psum[4] = {0.f, 0.f, 0.f, 0.f};

    stageKV(0, 0);
    stageKV(1, 1);

    for (int kt = 0; kt < 8; kt++) {
        asm volatile("s_waitcnt lgkmcnt(0)" ::: "memory");   // prev-iter LDS reads drained
        if (kt == 7) asm volatile("s_waitcnt vmcnt(0)" ::: "memory");
        else         asm volatile("s_waitcnt vmcnt(4)" ::: "memory");  // tile kt landed
        __builtin_amdgcn_s_barrier();
        __builtin_amdgcn_sched_barrier(0);

        const int buf = kt % 3;
        if (kt + 2 < 8) stageKV((kt + 2) % 3, kt + 2);   // into (kt-1)%3: readers drained

        // ---- S^T = K Q^T : Sc[mt][nt] rows=key(quad*4+rr), cols=q(lw) ----
        f32x4 Sc[4][4];
        #pragma unroll
        for (int mt = 0; mt < 4; mt++)
            #pragma unroll
            for (int nt = 0; nt < 4; nt++)
                Sc[mt][nt] = f32x4{0.f, 0.f, 0.f, 0.f};
        #pragma unroll
        for (int kk = 0; kk < 2; kk++)
            #pragma unroll
            for (int nt = 0; nt < 4; nt++) {
                f16x8 kf = *(const f16x8*)&Ks[buf][nt * 1024 + (kk * 4 + quad) * 128 + lw * 8];
                #pragma unroll
                for (int mt = 0; mt < 4; mt++)
                    Sc[mt][nt] = __builtin_amdgcn_mfma_f32_16x16x32_f16(kf, qf[mt][kk], Sc[mt][nt], 0, 0, 0);
            }

        // ---- P = exp(S*scale): f16x4 along key -> [qg][kchunk][qs][8] ----
        #pragma unroll
        for (int mt = 0; mt < 4; mt++)
            #pragma unroll
            for (int nt = 0; nt < 4; nt++) {
                f16x4 p4;
                #pragma unroll
                for (int rr = 0; rr < 4; rr++)
                    p4[rr] = (_Float16)__expf(Sc[mt][nt][rr] * 0.125f);
                *(f16x4*)&Pv[mt * 1024 + (nt * 2 + (quad >> 1)) * 128 + lw * 8 + (quad & 1) * 4] = p4;
            }
        asm volatile("s_waitcnt lgkmcnt(0)" ::: "memory");

        // ---- ctx += P V ; psum += rowsum(P) ----
        #pragma unroll
        for (int kk = 0; kk < 2; kk++) {
            f16x8 pf[4], vf[4];
            #pragma unroll
            for (int mt = 0; mt < 4; mt++) {
                pf[mt] = *(const f16x8*)&Pv[mt * 1024 + (kk * 4 + quad) * 128 + lw * 8];
                float s = 0.f;
                #pragma unroll
                for (int j = 0; j < 8; j++) s += (float)pf[mt][j];
                psum[mt] += s;
            }
            #pragma unroll
            for (int nt = 0; nt < 4; nt++)
                vf[nt] = *(const f16x8*)&Vs[buf][nt * 1024 + (kk * 4 + quad) * 128 + lw * 8];
            #pragma unroll
            for (int mt = 0; mt < 4; mt++)
                #pragma unroll
                for (int nt = 0; nt < 4; nt++)
                    cacc[mt][nt] = __builtin_amdgcn_mfma_f32_16x16x32_f16(pf[mt], vf[nt], cacc[mt][nt], 0, 0, 0);
        }
    }

    #pragma unroll
    for (int mt = 0; mt < 4; mt++) {
        psum[mt] += __shfl_xor(psum[mt], 16);
        psum[mt] += __shfl_xor(psum[mt], 32);
    }
    _Float16* Cg = ctx + ((size_t)(z * L + n * SEG + qh * 256 + wave * 64)) * D + h * HD;
    #pragma unroll
    for (int mt = 0; mt < 4; mt++)
        #pragma unroll
        for (int rr = 0; rr < 4; rr++) {
            float iv = 1.0f / __shfl(psum[mt], quad * 4 + rr);
            int q = mt * 16 + quad * 4 + rr;
            #pragma unroll
            for (int nt = 0; nt < 4; nt++)
                Cg[(size_t)q * D + nt * 16 + lw] = (_Float16)(cacc[mt][nt][rr] * iv);
        }
}

// ---------------------------------------------------------------------------
extern "C" void kernel_launch(void* const* d_in, const int* in_sizes, int n_in,
                              void* d_out, int out_size, void* d_ws, size_t ws_size,
                              hipStream_t stream)
{
    const float* x    = (const float*)d_in[0];
    const float* Wqkv = (const float*)d_in[1];
    const float* bqkv = (const float*)d_in[2];
    const float* Wout = (const float*)d_in[3];
    const float* bout = (const float*)d_in[4];

    float* out = (float*)d_out;

    constexpr size_t NX   = (size_t)Bb * S * D;      // 12.58M
    constexpr size_t NWQ  = (size_t)R * E3 * D;      //  7.08M
    constexpr size_t NWO  = (size_t)R * D * D;       //  2.36M
    constexpr size_t NTOK = (size_t)R * Bb * L;      // 16384

    _Float16* Xh  = (_Float16*)d_ws;
    _Float16* Wqh = Xh  + NX;
    _Float16* Wo  = Wqh + NWQ;
    _Float16* Qh  = Wo  + NWO;
    _Float16* Kh  = Qh  + NTOK * D;
    _Float16* Vt  = Kh  + NTOK * D;
    _Float16* ctx = Vt  + NTOK * D;                  // total ~145 MB

    conv_one<<<2048, 256, 0, stream>>>((const float4*)x, (f16x4*)Xh, (int)(NX / 4));
    conv_one<<<2048, 256, 0, stream>>>((const float4*)Wqkv, (f16x4*)Wqh, (int)(NWQ / 4));
    conv_one<<<1024, 256, 0, stream>>>((const float4*)Wout, (f16x4*)Wo, (int)(NWO / 4));

    mfma_gemm<0><<<E3 / 128 * (L / 128) * R * Bb, 256, 0, stream>>>(
        Xh, Wqh, bqkv, Qh, Kh, Vt, nullptr);

    attn_mfma<<<R * Bb * NSEG * H * 2, 256, 0, stream>>>(Qh, Kh, Vt, ctx);

    mfma_gemm<1><<<D / 128 * (L / 128) * R * Bb, 256, 0, stream>>>(
        ctx, Wo, bout, nullptr, nullptr, nullptr, out);
}